// Round 2
// baseline (11.086 us; speedup 1.0000x reference)
//
#include <hip/hip_runtime.h>

// out[0,n,b] = x_real[n ^ 2048, b]; out[1,n,b] = x_imag[n ^ 2048, b]
// = swap top/bottom halves of each [4096,512] f32 plane.
//
// In float4 units: H = half-plane = 2048*128 = 262144; src index = i ^ H.
// Thread t handles the pair (t, t+H) in both planes: pure register swap,
// 4 independent 16B loads + 4 independent 16B stores per thread (64 B each
// way) for max memory-level parallelism.

#define HALF4 262144              // half-plane in float4 (2048 rows * 128)
#define PLANE4 524288             // full plane in float4

__global__ __launch_bounds__(256) void swap_halves_kernel(
    const float4* __restrict__ xr,
    const float4* __restrict__ xi,
    float4* __restrict__ out)
{
    int t = blockIdx.x * blockDim.x + threadIdx.x;   // [0, HALF4)
    float4 a = xr[t];
    float4 b = xr[t + HALF4];
    float4 c = xi[t];
    float4 d = xi[t + HALF4];
    out[t]              = b;     // real plane, top half <- bottom
    out[t + HALF4]      = a;     // real plane, bottom half <- top
    out[PLANE4 + t]         = d; // imag plane
    out[PLANE4 + t + HALF4] = c;
}

extern "C" void kernel_launch(void* const* d_in, const int* in_sizes, int n_in,
                              void* d_out, int out_size, void* d_ws, size_t ws_size,
                              hipStream_t stream) {
    const float4* xr = (const float4*)d_in[0];
    const float4* xi = (const float4*)d_in[1];
    float4* out = (float4*)d_out;

    const int block = 256;
    const int grid = HALF4 / block;   // 1024 blocks
    swap_halves_kernel<<<grid, block, 0, stream>>>(xr, xi, out);
}